// Round 1
// 665.509 us; speedup vs baseline: 1.0503x; 1.0503x over previous
//
#include <hip/hip_runtime.h>
#include <stdint.h>

#define BB 8
#define LL 2048
#define DD 1024
#define HH 1024
#define BL (BB*LL)   // 16384

typedef __attribute__((ext_vector_type(8))) short short8;
typedef __attribute__((ext_vector_type(4))) float f32x4;

__device__ __forceinline__ unsigned short f2bf(float f) {
  unsigned int x = __float_as_uint(f);
  unsigned int r = (x + 0x7fffu + ((x >> 16) & 1u)) >> 16;
  return (unsigned short)r;
}
__device__ __forceinline__ float bf2f(unsigned short u) {
  return __uint_as_float(((unsigned int)u) << 16);
}

#define TM 128
#define TN 128
#define BK 64

struct __align__(16) Smem {
  unsigned short a[TM*BK];
  unsigned short b[TN*BK];
};

__device__ __forceinline__ void stage16(const unsigned short* g, unsigned short* l) {
  __builtin_amdgcn_global_load_lds((const __attribute__((address_space(1))) void*)g,
                                   (__attribute__((address_space(3))) void*)l,
                                   16, 0, 0);
}

// C[m,n] = sum_k A[m,k] * B[n,k]; A:[M,K] row-major, B:[N,K] row-major, bf16.
// XOR-swizzled LDS layout (verified: SQ_LDS_BANK_CONFLICT == 0).
__device__ __forceinline__ void gemm_core(const unsigned short* __restrict__ A, int lda,
                                          const unsigned short* __restrict__ B, int ldb,
                                          int m0, int n0, int ktiles,
                                          Smem* sm, f32x4 acc[4][4]) {
  const int tid  = threadIdx.x;
  const int lane = tid & 63;
  const int wave = tid >> 6;
  const int mw = (wave >> 1) * 64;
  const int nw = (wave & 1) * 64;
  const int srow = lane >> 3;                      // 0..7
  const int scol = (((lane & 7) ^ srow) * 8);      // swizzled source column
  const int fk = (lane >> 4) * 8;                  // frag k offset
  const int fr = lane & 15;                        // frag row
  const int fx = fr & 7;                           // swizzle key
  for (int kt = 0; kt < ktiles; ++kt) {
    const int k0 = kt * BK;
#pragma unroll
    for (int r = 0; r < 4; ++r) {
      const int chunk = wave * 4 + r;          // 0..15, wave-uniform
      const int row = chunk * 8 + srow;        // 0..127
      stage16(A + (size_t)(m0 + row) * lda + (k0 + scol), &sm->a[chunk * 512]);
      stage16(B + (size_t)(n0 + row) * ldb + (k0 + scol), &sm->b[chunk * 512]);
    }
    __syncthreads();
#pragma unroll
    for (int kk = 0; kk < BK; kk += 32) {
      const int kc = ((((kk + fk) >> 3) ^ fx) << 3);
      short8 af[4], bfv[4];
#pragma unroll
      for (int i = 0; i < 4; ++i)
        af[i] = *(const short8*)&sm->a[(mw + i*16 + fr) * BK + kc];
#pragma unroll
      for (int j = 0; j < 4; ++j)
        bfv[j] = *(const short8*)&sm->b[(nw + j*16 + fr) * BK + kc];
#pragma unroll
      for (int i = 0; i < 4; ++i)
#pragma unroll
        for (int j = 0; j < 4; ++j)
          acc[i][j] = __builtin_amdgcn_mfma_f32_16x16x32_bf16(af[i], bfv[j], acc[i][j], 0, 0, 0);
    }
    __syncthreads();
  }
}

__device__ __forceinline__ void acc_init(f32x4 acc[4][4]) {
#pragma unroll
  for (int i = 0; i < 4; ++i)
#pragma unroll
    for (int j = 0; j < 4; ++j)
      acc[i][j] = (f32x4){0.f, 0.f, 0.f, 0.f};
}

// per-element epilogue: body(rr, cc, av) with rr/cc = row/col within the 128x128 tile
template <typename F>
__device__ __forceinline__ void epilogue_loop(const f32x4 acc[4][4], F body) {
  const int lane_ = threadIdx.x & 63;
  const int wave_ = threadIdx.x >> 6;
  const int mw_ = (wave_ >> 1) * 64, nw_ = (wave_ & 1) * 64;
#pragma unroll
  for (int mi = 0; mi < 4; ++mi)
#pragma unroll
    for (int ni = 0; ni < 4; ++ni)
#pragma unroll
      for (int j = 0; j < 4; ++j) {
        const int rr = mw_ + mi * 16 + ((lane_ >> 4) << 2) + j;
        const int cc = nw_ + ni * 16 + (lane_ & 15);
        body(rr, cc, acc[mi][ni][j]);
      }
}

// XCD supertile remap for (8 x 128) grids over M-tiles 0..15 per batch, N-tiles 0..7.
// linear id = x + 8*i -> xcd = x (round-robin). Each XCD owns a 4mt x 2nt group:
// A-panels refetched x2 (was x8), B-panels x4 (was x1, but B is small/L2-hot).
__device__ __forceinline__ void xcd_map_u(int x, int i, int& bb, int& mt, int& nt) {
  bb = i >> 4;
  const int i16 = i & 15;
  const int sr = x >> 1, sc = x & 1;
  mt = 4 * (i16 & 3) + sr;      // 0..15
  nt = 4 * sc + (i16 >> 2);     // 0..7
}

// ---------------- prep kernels ----------------

// one wave per row: bf16-convert x, and dot with w_lr / w_wd
__global__ void k_prep_x(const float* __restrict__ x, const float* __restrict__ wlr,
                         const float* __restrict__ wwd, unsigned short* __restrict__ xb,
                         float* __restrict__ lrlog, float* __restrict__ wdlog) {
  const int wave = threadIdx.x >> 6, lane = threadIdx.x & 63;
  const int row = blockIdx.x * 4 + wave;
  const float* xr = x + (size_t)row * DD;
  float s1 = 0.f, s2 = 0.f;
#pragma unroll
  for (int ch = 0; ch < 4; ++ch) {
    const int col = ch * 256 + lane * 4;
    float4 v = *(const float4*)(xr + col);
    float4 a = *(const float4*)(wlr + col);
    float4 b = *(const float4*)(wwd + col);
    s1 += v.x*a.x + v.y*a.y + v.z*a.z + v.w*a.w;
    s2 += v.x*b.x + v.y*b.y + v.z*b.z + v.w*b.w;
    uint2 u;
    u.x = (unsigned)f2bf(v.x) | ((unsigned)f2bf(v.y) << 16);
    u.y = (unsigned)f2bf(v.z) | ((unsigned)f2bf(v.w) << 16);
    *(uint2*)(xb + (size_t)row * DD + col) = u;
  }
#pragma unroll
  for (int off = 32; off > 0; off >>= 1) {
    s1 += __shfl_down(s1, off);
    s2 += __shfl_down(s2, off);
  }
  if (lane == 0) { lrlog[row] = s1; wdlog[row] = s2; }
}

// z=0..2: transpose+convert w_q, w_k, w_v (negated) to [N,K] bf16
// z=3: straight bf16 convert of w_k (row-major [j][h], B-operand for M2 fold)
__global__ void k_prep_w(const float* __restrict__ wq, const float* __restrict__ wk,
                         const float* __restrict__ wv, unsigned short* __restrict__ wqt,
                         unsigned short* __restrict__ wkt, unsigned short* __restrict__ wvtn,
                         unsigned short* __restrict__ wkr) {
  const int idx = blockIdx.x * 256 + threadIdx.x;   // over 1024*1024
  if (blockIdx.z == 3) { wkr[idx] = f2bf(wk[idx]); return; }
  const int k = idx >> 10, n = idx & 1023;          // output-linear [n][k], read coalesced over n
  const float* src = (blockIdx.z == 0) ? wq : (blockIdx.z == 1) ? wk : wv;
  unsigned short* dst = (blockIdx.z == 0) ? wqt : (blockIdx.z == 1) ? wkt : wvtn;
  float v = src[(size_t)k * 1024 + n];
  if (blockIdx.z == 2) v = -v;
  dst[(size_t)n * 1024 + k] = f2bf(v);
}

// straight convert hidden -> bf16
__global__ void k_prep_h(const float* __restrict__ hid, unsigned short* __restrict__ wpb) {
  const size_t i = ((size_t)blockIdx.x * 256 + threadIdx.x) * 4;
  float4 v = *(const float4*)(hid + i);
  uint2 u;
  u.x = (unsigned)f2bf(v.x) | ((unsigned)f2bf(v.y) << 16);
  u.y = (unsigned)f2bf(v.z) | ((unsigned)f2bf(v.w) << 16);
  *(uint2*)(wpb + i) = u;
}

// bias2[b][d] = sum_h bk[h]*Wp[b,d,h] - bv[d]   (for the folded U GEMM)
__global__ void k_bias2(const unsigned short* __restrict__ wpb, const float* __restrict__ bk,
                        const float* __restrict__ bv, float* __restrict__ bias2) {
  const int wave = threadIdx.x >> 6, lane = threadIdx.x & 63;
  const int row = blockIdx.x * 4 + wave;            // over BB*DD = 8192
  const unsigned short* wr = wpb + (size_t)row * HH;
  float s = 0.f;
#pragma unroll
  for (int ch = 0; ch < 4; ++ch) {
    const int col = ch * 256 + lane * 4;
    float4 a = *(const float4*)(bk + col);
    ushort4 u = *(const ushort4*)(wr + col);
    s += a.x * bf2f(u.x) + a.y * bf2f(u.y) + a.z * bf2f(u.z) + a.w * bf2f(u.w);
  }
#pragma unroll
  for (int off = 32; off > 0; off >>= 1) s += __shfl_down(s, off);
  if (lane == 0) bias2[row] = s - bv[row & 1023];
}

// per-batch scan: lr, c = cumsum(log_wd), s = lr*exp(c_last - c), ecl = exp(c_last)
__global__ void k_scan(const float* __restrict__ lrlog, const float* __restrict__ wdlog,
                       const float* __restrict__ lbl, const float* __restrict__ blr,
                       const float* __restrict__ lbw, const float* __restrict__ bwd,
                       float* __restrict__ lr, float* __restrict__ c,
                       float* __restrict__ s, float* __restrict__ ecl) {
  const int b = blockIdx.x, t = threadIdx.x;
  __shared__ float sums[256];
  const float elr = expf(lbl[0]);
  const float ewd = expf(lbw[0]);
  const float blr0 = blr[0], bwd0 = bwd[0];
  float lw[8];
  const float* wb = wdlog + (size_t)b * LL + t * 8;
  float tot = 0.f;
#pragma unroll
  for (int i = 0; i < 8; ++i) {
    float z = wb[i] + bwd0;
    float sig = 1.f / (1.f + expf(-z));
    tot += log1pf(-ewd * sig);
    lw[i] = tot;                      // inclusive local prefix
  }
  sums[t] = tot;
  __syncthreads();
  for (int off = 1; off < 256; off <<= 1) {
    float v = (t >= off) ? sums[t - off] : 0.f;
    __syncthreads();
    sums[t] += v;
    __syncthreads();
  }
  const float prev = (t > 0) ? sums[t - 1] : 0.f;
  const float ctot = sums[255];
  const float* lb = lrlog + (size_t)b * LL + t * 8;
#pragma unroll
  for (int i = 0; i < 8; ++i) {
    const int idx = b * LL + t * 8 + i;
    const float ci = prev + lw[i];
    c[idx] = ci;
    float zl = lb[i] + blr0;
    float lri = elr / (1.f + expf(-zl));
    lr[idx] = lri;
    s[idx] = lri * expf(ctot - ci);
  }
  if (t == 0) ecl[b] = expf(ctot);
}

// ---------------- GEMM kernels ----------------

// W2T[b][d][j] = sum_h Wp[b,d,h]*Wk[j,h] - Wv[j,d]   (bf16; folds K@Wp^T into one GEMM)
__global__ __launch_bounds__(256) void k_gemm_m2(const unsigned short* __restrict__ wpb,
    const unsigned short* __restrict__ wkr, const unsigned short* __restrict__ wvtn,
    unsigned short* __restrict__ w2t) {
  const int b = blockIdx.z, mt = blockIdx.y, nt = blockIdx.x;
  __shared__ Smem sm;
  f32x4 acc[4][4]; acc_init(acc);
  gemm_core(wpb + (size_t)b * DD * HH, HH, wkr, HH, mt * TM, nt * TN, HH / BK, &sm, acc);
  epilogue_loop(acc, [&](int rr, int cc, float av) {
    const int d = mt * TM + rr, j = nt * TN + cc;
    const size_t gi = (size_t)d * DD + j;
    w2t[(size_t)b * DD * DD + gi] = f2bf(av + bf2f(wvtn[gi]));   // wvtn = -Wv^T
  });
}

// Q = X*WqT + bq; also q2 = exp(c[m]) * Q  (feeds y_cross = q2 * Wp^T)
__global__ __launch_bounds__(256) void k_gemm_q(const unsigned short* __restrict__ xb,
    const unsigned short* __restrict__ wt, const float* __restrict__ bias,
    const float* __restrict__ c, unsigned short* __restrict__ outb,
    unsigned short* __restrict__ q2b) {
  int bb, mt, nt; xcd_map_u(blockIdx.x, blockIdx.y, bb, mt, nt);
  const int m0 = (bb * 16 + mt) * TM, n0 = nt * TN;
  __shared__ Smem sm;
  f32x4 acc[4][4]; acc_init(acc);
  gemm_core(xb, DD, wt, DD, m0, n0, DD / BK, &sm, acc);
  epilogue_loop(acc, [&](int rr, int cc, float av) {
    const int row = m0 + rr, col = n0 + cc;
    const float v = av + bias[col];
    outb[(size_t)row * HH + col] = f2bf(v);
    q2b[(size_t)row * HH + col] = f2bf(v * __expf(c[row]));
  });
}

__global__ __launch_bounds__(256) void k_gemm_k(const unsigned short* __restrict__ xb,
    const unsigned short* __restrict__ wt, const float* __restrict__ bias,
    const float* __restrict__ s, unsigned short* __restrict__ kb,
    unsigned short* __restrict__ k2t) {
  int bb, mt, nt; xcd_map_u(blockIdx.x, blockIdx.y, bb, mt, nt);
  const int m0 = (bb * 16 + mt) * TM, n0 = nt * TN;
  __shared__ Smem sm;
  f32x4 acc[4][4]; acc_init(acc);
  gemm_core(xb, DD, wt, DD, m0, n0, DD / BK, &sm, acc);
  const int lane = threadIdx.x & 63, wave = threadIdx.x >> 6;
  const int mw = (wave >> 1) * 64, nw = (wave & 1) * 64;
#pragma unroll
  for (int mi = 0; mi < 4; ++mi)
#pragma unroll
    for (int ni = 0; ni < 4; ++ni) {
      const int col = n0 + nw + ni*16 + (lane & 15);
      const float bias_c = bias[col];
      const int row0 = m0 + mw + mi*16 + ((lane >> 4) << 2);
      const int b = row0 >> 11, ml0 = row0 & 2047;
      unsigned short tmp[4];
#pragma unroll
      for (int j = 0; j < 4; ++j) {
        float v = acc[mi][ni][j] + bias_c;
        kb[(size_t)(row0 + j) * HH + col] = f2bf(v);
        tmp[j] = f2bf(v * s[row0 + j]);
      }
      uint2 u;
      u.x = (unsigned)tmp[0] | ((unsigned)tmp[1] << 16);
      u.y = (unsigned)tmp[2] | ((unsigned)tmp[3] << 16);
      *(uint2*)&k2t[((size_t)b * HH + col) * LL + ml0] = u;
    }
}

// U = X*W2T + bias2, stored transposed: ut[b][d][l]  (single K=1024 pass via W2 fold)
__global__ __launch_bounds__(256) void k_gemm_u(const unsigned short* __restrict__ xb,
    const unsigned short* __restrict__ w2t, const float* __restrict__ bias2,
    unsigned short* __restrict__ ut) {
  int bb, mt, nt; xcd_map_u(blockIdx.x, blockIdx.y, bb, mt, nt);
  const int m0 = (bb * 16 + mt) * TM, n0 = nt * TN;
  const int b = bb;
  __shared__ Smem sm;
  f32x4 acc[4][4]; acc_init(acc);
  gemm_core(xb, DD, w2t + (size_t)b * DD * DD, DD, m0, n0, DD / BK, &sm, acc);
  const int lane = threadIdx.x & 63, wave = threadIdx.x >> 6;
  const int mw = (wave >> 1) * 64, nw = (wave & 1) * 64;
#pragma unroll
  for (int mi = 0; mi < 4; ++mi)
#pragma unroll
    for (int ni = 0; ni < 4; ++ni) {
      const int col = n0 + nw + ni*16 + (lane & 15);
      const float b2c = bias2[b * DD + col];
      const int row0 = m0 + mw + mi*16 + ((lane >> 4) << 2);
      const int ml0 = row0 & 2047;
      unsigned short tmp[4];
#pragma unroll
      for (int j = 0; j < 4; ++j) tmp[j] = f2bf(acc[mi][ni][j] + b2c);
      uint2 u;
      u.x = (unsigned)tmp[0] | ((unsigned)tmp[1] << 16);
      u.y = (unsigned)tmp[2] | ((unsigned)tmp[3] << 16);
      *(uint2*)&ut[((size_t)b * DD + col) * LL + ml0] = u;
    }
}

// pb[m,l] = -lr[l]*exp(c[m]-c[l]) * (Q K^T)[m,l]  (negated so y accumulates additively)
// lower-triangular tiles only; XCD-contiguous tile grouping for L2 locality
__global__ __launch_bounds__(256) void k_gemm_p(const unsigned short* __restrict__ qb,
    const unsigned short* __restrict__ kb, const float* __restrict__ lr,
    const float* __restrict__ c, unsigned short* __restrict__ pb) {
  const int b = blockIdx.z;
  // remap so each XCD (blockIdx.x % 8 round-robin) gets a contiguous triangular range
  const int i = blockIdx.x;                    // 0..135
  const int t = (i & 7) * 17 + (i >> 3);       // 136 = 8 * 17
  int mt = (int)((sqrtf(8.0f * (float)t + 1.0f) - 1.0f) * 0.5f);
  while ((mt + 1) * (mt + 2) / 2 <= t) ++mt;
  while (mt * (mt + 1) / 2 > t) --mt;
  const int nt = t - mt * (mt + 1) / 2;
  __shared__ Smem sm;
  f32x4 acc[4][4]; acc_init(acc);
  const int base = b * LL;
  const int m0g = base + mt * TM, n0g = base + nt * TN;
  gemm_core(qb, HH, kb, HH, m0g, n0g, HH / BK, &sm, acc);

  const int lane = threadIdx.x & 63, wave = threadIdx.x >> 6;
  const int mw = (wave >> 1) * 64, nw = (wave & 1) * 64;
  if (nt != mt) {
    // off-diagonal: factored decay, both exp args <= 0 (c monotone decreasing)
    const float cref = c[base + mt * TM];
    float er[4][4], fc[4];
#pragma unroll
    for (int mi = 0; mi < 4; ++mi)
#pragma unroll
      for (int j = 0; j < 4; ++j) {
        const int m = mt * TM + mw + mi*16 + ((lane >> 4) << 2) + j;
        er[mi][j] = __expf(c[base + m] - cref);
      }
#pragma unroll
    for (int ni = 0; ni < 4; ++ni) {
      const int l = nt * TN + nw + ni*16 + (lane & 15);
      fc[ni] = lr[base + l] * __expf(cref - c[base + l]);
    }
#pragma unroll
    for (int mi = 0; mi < 4; ++mi)
#pragma unroll
      for (int ni = 0; ni < 4; ++ni) {
        const int l = nt * TN + nw + ni*16 + (lane & 15);
        const int row0 = mt * TM + mw + mi*16 + ((lane >> 4) << 2);
#pragma unroll
        for (int j = 0; j < 4; ++j) {
          const float v = -acc[mi][ni][j] * er[mi][j] * fc[ni];
          pb[((size_t)base + row0 + j) * LL + l] = f2bf(v);
        }
      }
  } else {
    // diagonal tile: direct form (factored version can overflow the col factor)
    epilogue_loop(acc, [&](int rr, int cc, float av) {
      const int m = mt * TM + rr, l = nt * TN + cc;
      float v = 0.f;
      if (l <= m) v = -av * lr[base + l] * __expf(c[base + m] - c[base + l]);
      pb[((size_t)base + m) * LL + l] = f2bf(v);
    });
  }
}

// y = pb*U + q2*Wp^T  (pb already negated; cross folded in)
// XCD supertile: each XCD owns mt quad {sr,7-sr,8+sr,15-sr} (exactly K-balanced)
// x 2 nt tiles; heavy-mt first to kill the makespan tail.
__global__ __launch_bounds__(256) void k_gemm_y(const unsigned short* __restrict__ pb,
    const unsigned short* __restrict__ ut, const unsigned short* __restrict__ q2b,
    const unsigned short* __restrict__ wpb, float* __restrict__ out) {
  const int b = blockIdx.z;
  const int x = blockIdx.x, i16 = blockIdx.y;
  const int sr = x >> 1, sc = x & 1;
  const int lm = i16 & 3, ln = i16 >> 2;
  const int mt = (lm == 0) ? (15 - sr) : (lm == 1) ? (8 + sr)
               : (lm == 2) ? (7 - sr)  : sr;
  const int nt = 4 * sc + ln;
  __shared__ Smem sm;
  f32x4 acc[4][4]; acc_init(acc);
  gemm_core(pb + (size_t)b * LL * LL, LL, ut + (size_t)b * DD * LL, LL,
            mt * TM, nt * TN, (mt + 1) * 2, &sm, acc);
  gemm_core(q2b, HH, wpb + (size_t)b * DD * HH, HH,
            b * LL + mt * TM, nt * TN, HH / BK, &sm, acc);
  epilogue_loop(acc, [&](int rr, int cc, float av) {
    const int m = mt * TM + rr, d = nt * TN + cc;
    out[((size_t)b * LL + m) * DD + d] = av;
  });
}

// W_next = -Ut * K2t^T + ecl[b]*W_prev   (XCD supertile: 4mt x 2nt per XCD)
__global__ __launch_bounds__(256) void k_gemm_wn(const unsigned short* __restrict__ ut,
    const unsigned short* __restrict__ k2t, const float* __restrict__ hid,
    const float* __restrict__ ecl, float* __restrict__ out2) {
  const int b = blockIdx.z;
  const int x = blockIdx.x, i8 = blockIdx.y;
  const int sr = x >> 2, sc = x & 3;
  const int mt = 4 * sr + (i8 & 3);
  const int nt = 2 * sc + (i8 >> 2);
  __shared__ Smem sm;
  f32x4 acc[4][4]; acc_init(acc);
  gemm_core(ut + (size_t)b * DD * LL, LL, k2t + (size_t)b * HH * LL, LL,
            mt * TM, nt * TN, LL / BK, &sm, acc);
  epilogue_loop(acc, [&](int rr, int cc, float av) {
    const int d = mt * TM + rr, h = nt * TN + cc;
    const size_t gi = ((size_t)b * DD + d) * HH + h;
    out2[gi] = -av + ecl[b] * hid[gi];
  });
}

// ---------------- launcher ----------------

extern "C" void kernel_launch(void* const* d_in, const int* in_sizes, int n_in,
                              void* d_out, int out_size, void* d_ws, size_t ws_size,
                              hipStream_t stream) {
  (void)in_sizes; (void)n_in; (void)out_size; (void)ws_size;
  const float* x   = (const float*)d_in[0];
  const float* hid = (const float*)d_in[1];
  const float* lbl = (const float*)d_in[2];
  const float* wlr = (const float*)d_in[3];
  const float* blr = (const float*)d_in[4];
  const float* lbw = (const float*)d_in[5];
  const float* wwd = (const float*)d_in[6];
  const float* bwd = (const float*)d_in[7];
  const float* wq  = (const float*)d_in[8];
  const float* bq  = (const float*)d_in[9];
  const float* wk  = (const float*)d_in[10];
  const float* bk  = (const float*)d_in[11];
  const float* wv  = (const float*)d_in[12];
  const float* bv  = (const float*)d_in[13];
  float* out = (float*)d_out;

  char* w = (char*)d_ws;
  constexpr size_t SZ_XB  = (size_t)BL * DD * 2;       // 33.5 MB
  constexpr size_t SZ_QB  = (size_t)BL * HH * 2;
  constexpr size_t SZ_KB  = (size_t)BL * HH * 2;
  constexpr size_t SZ_K2T = (size_t)BB * HH * LL * 2;
  constexpr size_t SZ_UT  = (size_t)BB * DD * LL * 2;
  constexpr size_t SZ_PB  = (size_t)BB * LL * LL * 2;  // 67 MB
  constexpr size_t SZ_WT  = (size_t)DD * HH * 2;
  constexpr size_t SZ_WPB = (size_t)BB * DD * HH * 2;
  constexpr size_t SZ_V16 = (size_t)BL * 4;            // 64 KB fp32 vectors

  size_t off = 0;
  unsigned short* xb   = (unsigned short*)(w + off); off += SZ_XB;
  unsigned short* qb   = (unsigned short*)(w + off); off += SZ_QB;
  unsigned short* kb   = (unsigned short*)(w + off); off += SZ_KB;
  unsigned short* k2t  = (unsigned short*)(w + off); off += SZ_K2T;
  unsigned short* ut   = (unsigned short*)(w + off); off += SZ_UT;
  unsigned short* pb   = (unsigned short*)(w + off); off += SZ_PB;
  unsigned short* wqt  = (unsigned short*)(w + off); off += SZ_WT;
  unsigned short* wkt  = (unsigned short*)(w + off); off += SZ_WT;
  unsigned short* wvtn = (unsigned short*)(w + off); off += SZ_WT;
  unsigned short* wpb  = (unsigned short*)(w + off); off += SZ_WPB;
  float* lrlog = (float*)(w + off); off += SZ_V16;
  float* wdlog = (float*)(w + off); off += SZ_V16;
  float* lr    = (float*)(w + off); off += SZ_V16;
  float* c     = (float*)(w + off); off += SZ_V16;
  float* s     = (float*)(w + off); off += SZ_V16;
  float* ecl   = (float*)(w + off); off += 256;
  float* bias2 = (float*)(w + off); off += (size_t)BB * DD * 4;   // 32 KB

  // w2t (16.8 MB) + wkr (2 MB) alias the pb region: dead before k_gemm_p writes pb.
  unsigned short* w2t = pb;
  unsigned short* wkr = pb + (size_t)BB * DD * DD;

  // q2 scratch lives in d_out's W_next region (bf16 16.8M elems == fp32 8.4M elems);
  // written by k_gemm_q, read by k_gemm_y, overwritten by k_gemm_wn afterwards.
  unsigned short* q2b = (unsigned short*)(out + (size_t)BL * DD);
  float* out2 = out + (size_t)BL * DD;

  k_prep_x<<<dim3(BL / 4), 256, 0, stream>>>(x, wlr, wwd, xb, lrlog, wdlog);
  k_prep_w<<<dim3(4096, 1, 4), 256, 0, stream>>>(wq, wk, wv, wqt, wkt, wvtn, wkr);
  k_prep_h<<<dim3((unsigned)((size_t)BB * DD * HH / 1024)), 256, 0, stream>>>(hid, wpb);
  k_scan<<<dim3(BB), 256, 0, stream>>>(lrlog, wdlog, lbl, blr, lbw, bwd, lr, c, s, ecl);
  k_bias2<<<dim3(BB * DD / 4), 256, 0, stream>>>(wpb, bk, bv, bias2);

  k_gemm_m2<<<dim3(DD / TN, DD / TM, BB), 256, 0, stream>>>(wpb, wkr, wvtn, w2t);
  k_gemm_q<<<dim3(8, BL / TM / 16 * 16), 256, 0, stream>>>(xb, wqt, bq, c, qb, q2b);
  k_gemm_k<<<dim3(8, BL / TM), 256, 0, stream>>>(xb, wkt, bk, s, kb, k2t);
  k_gemm_u<<<dim3(8, BL / TM), 256, 0, stream>>>(xb, w2t, bias2, ut);
  k_gemm_p<<<dim3(136, 1, BB), 256, 0, stream>>>(qb, kb, lr, c, pb);
  k_gemm_y<<<dim3(8, 16, BB), 256, 0, stream>>>(pb, ut, q2b, wpb, out);
  k_gemm_wn<<<dim3(8, 8, BB), 256, 0, stream>>>(ut, k2t, hid, ecl, out2);
}

// Round 2
// 628.436 us; speedup vs baseline: 1.1122x; 1.0590x over previous
//
#include <hip/hip_runtime.h>
#include <stdint.h>

#define BB 8
#define LL 2048
#define DD 1024
#define HH 1024
#define BL (BB*LL)   // 16384

typedef __attribute__((ext_vector_type(8))) short short8;
typedef __attribute__((ext_vector_type(4))) float f32x4;

__device__ __forceinline__ unsigned short f2bf(float f) {
  unsigned int x = __float_as_uint(f);
  unsigned int r = (x + 0x7fffu + ((x >> 16) & 1u)) >> 16;
  return (unsigned short)r;
}
__device__ __forceinline__ float bf2f(unsigned short u) {
  return __uint_as_float(((unsigned int)u) << 16);
}

__device__ __forceinline__ void stage16(const unsigned short* g, unsigned short* l) {
  __builtin_amdgcn_global_load_lds((const __attribute__((address_space(1))) void*)g,
                                   (__attribute__((address_space(3))) void*)l,
                                   16, 0, 0);
}

// ================= old 128x128 core (kept for k_gemm_p) =================
#define TM 128
#define TN 128
#define BK 64

struct __align__(16) Smem {
  unsigned short a[TM*BK];
  unsigned short b[TN*BK];
};

__device__ __forceinline__ void gemm_core(const unsigned short* __restrict__ A, int lda,
                                          const unsigned short* __restrict__ B, int ldb,
                                          int m0, int n0, int ktiles,
                                          Smem* sm, f32x4 acc[4][4]) {
  const int tid  = threadIdx.x;
  const int lane = tid & 63;
  const int wave = tid >> 6;
  const int mw = (wave >> 1) * 64;
  const int nw = (wave & 1) * 64;
  const int srow = lane >> 3;
  const int scol = (((lane & 7) ^ srow) * 8);
  const int fk = (lane >> 4) * 8;
  const int fr = lane & 15;
  const int fx = fr & 7;
  for (int kt = 0; kt < ktiles; ++kt) {
    const int k0 = kt * BK;
#pragma unroll
    for (int r = 0; r < 4; ++r) {
      const int chunk = wave * 4 + r;
      const int row = chunk * 8 + srow;
      stage16(A + (size_t)(m0 + row) * lda + (k0 + scol), &sm->a[chunk * 512]);
      stage16(B + (size_t)(n0 + row) * ldb + (k0 + scol), &sm->b[chunk * 512]);
    }
    __syncthreads();
#pragma unroll
    for (int kk = 0; kk < BK; kk += 32) {
      const int kc = ((((kk + fk) >> 3) ^ fx) << 3);
      short8 af[4], bfv[4];
#pragma unroll
      for (int i = 0; i < 4; ++i)
        af[i] = *(const short8*)&sm->a[(mw + i*16 + fr) * BK + kc];
#pragma unroll
      for (int j = 0; j < 4; ++j)
        bfv[j] = *(const short8*)&sm->b[(nw + j*16 + fr) * BK + kc];
#pragma unroll
      for (int i = 0; i < 4; ++i)
#pragma unroll
        for (int j = 0; j < 4; ++j)
          acc[i][j] = __builtin_amdgcn_mfma_f32_16x16x32_bf16(af[i], bfv[j], acc[i][j], 0, 0, 0);
    }
    __syncthreads();
  }
}

__device__ __forceinline__ void acc_init(f32x4 acc[4][4]) {
#pragma unroll
  for (int i = 0; i < 4; ++i)
#pragma unroll
    for (int j = 0; j < 4; ++j)
      acc[i][j] = (f32x4){0.f, 0.f, 0.f, 0.f};
}

template <typename F>
__device__ __forceinline__ void epilogue_loop(const f32x4 acc[4][4], F body) {
  const int lane_ = threadIdx.x & 63;
  const int wave_ = threadIdx.x >> 6;
  const int mw_ = (wave_ >> 1) * 64, nw_ = (wave_ & 1) * 64;
#pragma unroll
  for (int mi = 0; mi < 4; ++mi)
#pragma unroll
    for (int ni = 0; ni < 4; ++ni)
#pragma unroll
      for (int j = 0; j < 4; ++j) {
        const int rr = mw_ + mi * 16 + ((lane_ >> 4) << 2) + j;
        const int cc = nw_ + ni * 16 + (lane_ & 15);
        body(rr, cc, acc[mi][ni][j]);
      }
}

// ================= new 2-phase double-buffered core =================
// 512 threads = 8 waves (2M x 4N). BM = MI*32 (MI=8 -> 256, MI=4 -> 128),
// BN = 256, BK = 64. LDS double-buffered; same XOR swizzle as the 128^2 core
// (SQ_LDS_BANK_CONFLICT == 0 verified). T3 "minimum 2-phase": stage(kt+1)
// into the other buffer BEFORE computing kt; one vmcnt(0)+s_barrier per
// K-tile. Raw s_barrier + sched_barrier(0) so the compiler can neither
// hoist ds_reads above the barrier nor insert a conservative vmcnt drain
// before the MFMA ds_reads (rule 18 / LDS-DMA aliasing).
template<int MI>
struct __align__(16) Smem2 {
  unsigned short a[2][MI*2048];   // BM x 64 per buffer
  unsigned short b[2][16384];     // 256 x 64 per buffer
};

template<int MI>
__device__ __forceinline__ void acc_init2(f32x4 (&acc)[MI][4]) {
#pragma unroll
  for (int i = 0; i < MI; ++i)
#pragma unroll
    for (int j = 0; j < 4; ++j)
      acc[i][j] = (f32x4){0.f, 0.f, 0.f, 0.f};
}

template<int MI, class FA, class FB>
__device__ __forceinline__ void gemm2_core(FA srcA, FB srcB, int NK,
                                           Smem2<MI>* sm, f32x4 (&acc)[MI][4]) {
  const int lane = threadIdx.x & 63;
  const int wave = threadIdx.x >> 6;           // 0..7
  const int srow = lane >> 3;                  // 0..7
  const int scol = ((lane & 7) ^ srow) * 8;    // swizzled source column
  constexpr int APW = MI / 2;                  // A chunks per wave
  const int fk = (lane >> 4) * 8;
  const int fr = lane & 15;
  const int fx = fr & 7;
  const int mwr = (wave >> 2) * (MI * 16);     // wave row base (0 / BM/2)
  const int nwr = (wave & 3) * 64;             // wave col base

  auto STAGE = [&](int p, int kt) {
#pragma unroll
    for (int r = 0; r < APW; ++r) {
      const int chunk = wave * APW + r;        // 0..BM/8-1, wave-uniform
      stage16(srcA(chunk * 8 + srow, kt) + scol, &sm->a[p][chunk * 512]);
    }
#pragma unroll
    for (int r = 0; r < 4; ++r) {
      const int chunk = wave * 4 + r;          // 0..31
      stage16(srcB(chunk * 8 + srow, kt) + scol, &sm->b[p][chunk * 512]);
    }
  };
  auto COMPUTE = [&](int p) {
    const unsigned short* pa  = sm->a[p];
    const unsigned short* pbp = sm->b[p];
#pragma unroll
    for (int kk = 0; kk < 64; kk += 32) {
      const int kc = ((((kk + fk) >> 3) ^ fx) << 3);
      short8 af[MI], bfv[4];
#pragma unroll
      for (int i = 0; i < MI; ++i)
        af[i] = *(const short8*)&pa[(mwr + i*16 + fr) * 64 + kc];
#pragma unroll
      for (int j = 0; j < 4; ++j)
        bfv[j] = *(const short8*)&pbp[(nwr + j*16 + fr) * 64 + kc];
#pragma unroll
      for (int i = 0; i < MI; ++i)
#pragma unroll
        for (int j = 0; j < 4; ++j)
          acc[i][j] = __builtin_amdgcn_mfma_f32_16x16x32_bf16(af[i], bfv[j], acc[i][j], 0, 0, 0);
    }
  };

  STAGE(0, 0);
  asm volatile("s_waitcnt vmcnt(0)" ::: "memory");
  __builtin_amdgcn_s_barrier();
  __builtin_amdgcn_sched_barrier(0);
  int cur = 0;
  for (int kt = 0; kt < NK - 1; ++kt) {
    STAGE(cur ^ 1, kt + 1);      // loads land in the idle buffer; latency
    COMPUTE(cur);                // hides under 2*MI*4 MFMAs
    asm volatile("s_waitcnt vmcnt(0)" ::: "memory");
    __builtin_amdgcn_s_barrier();
    __builtin_amdgcn_sched_barrier(0);
    cur ^= 1;
  }
  COMPUTE(cur);
}

// per-element epilogue for the 2ph core
template<int MI, typename F>
__device__ __forceinline__ void epi2(const f32x4 (&acc)[MI][4], F body) {
  const int lane = threadIdx.x & 63;
  const int wave = threadIdx.x >> 6;
  const int mwr = (wave >> 2) * (MI * 16), nwr = (wave & 3) * 64;
#pragma unroll
  for (int i = 0; i < MI; ++i)
#pragma unroll
    for (int j = 0; j < 4; ++j)
#pragma unroll
      for (int jj = 0; jj < 4; ++jj) {
        const int rr = mwr + i * 16 + ((lane >> 4) << 2) + jj;
        const int cc = nwr + j * 16 + (lane & 15);
        body(rr, cc, acc[i][j][jj]);
      }
}

// ---------------- prep kernels ----------------

__global__ void k_prep_x(const float* __restrict__ x, const float* __restrict__ wlr,
                         const float* __restrict__ wwd, unsigned short* __restrict__ xb,
                         float* __restrict__ lrlog, float* __restrict__ wdlog) {
  const int wave = threadIdx.x >> 6, lane = threadIdx.x & 63;
  const int row = blockIdx.x * 4 + wave;
  const float* xr = x + (size_t)row * DD;
  float s1 = 0.f, s2 = 0.f;
#pragma unroll
  for (int ch = 0; ch < 4; ++ch) {
    const int col = ch * 256 + lane * 4;
    float4 v = *(const float4*)(xr + col);
    float4 a = *(const float4*)(wlr + col);
    float4 b = *(const float4*)(wwd + col);
    s1 += v.x*a.x + v.y*a.y + v.z*a.z + v.w*a.w;
    s2 += v.x*b.x + v.y*b.y + v.z*b.z + v.w*b.w;
    uint2 u;
    u.x = (unsigned)f2bf(v.x) | ((unsigned)f2bf(v.y) << 16);
    u.y = (unsigned)f2bf(v.z) | ((unsigned)f2bf(v.w) << 16);
    *(uint2*)(xb + (size_t)row * DD + col) = u;
  }
#pragma unroll
  for (int off = 32; off > 0; off >>= 1) {
    s1 += __shfl_down(s1, off);
    s2 += __shfl_down(s2, off);
  }
  if (lane == 0) { lrlog[row] = s1; wdlog[row] = s2; }
}

__global__ void k_prep_w(const float* __restrict__ wq, const float* __restrict__ wk,
                         const float* __restrict__ wv, unsigned short* __restrict__ wqt,
                         unsigned short* __restrict__ wkt, unsigned short* __restrict__ wvtn,
                         unsigned short* __restrict__ wkr) {
  const int idx = blockIdx.x * 256 + threadIdx.x;
  if (blockIdx.z == 3) { wkr[idx] = f2bf(wk[idx]); return; }
  const int k = idx >> 10, n = idx & 1023;
  const float* src = (blockIdx.z == 0) ? wq : (blockIdx.z == 1) ? wk : wv;
  unsigned short* dst = (blockIdx.z == 0) ? wqt : (blockIdx.z == 1) ? wkt : wvtn;
  float v = src[(size_t)k * 1024 + n];
  if (blockIdx.z == 2) v = -v;
  dst[(size_t)n * 1024 + k] = f2bf(v);
}

__global__ void k_prep_h(const float* __restrict__ hid, unsigned short* __restrict__ wpb) {
  const size_t i = ((size_t)blockIdx.x * 256 + threadIdx.x) * 4;
  float4 v = *(const float4*)(hid + i);
  uint2 u;
  u.x = (unsigned)f2bf(v.x) | ((unsigned)f2bf(v.y) << 16);
  u.y = (unsigned)f2bf(v.z) | ((unsigned)f2bf(v.w) << 16);
  *(uint2*)(wpb + i) = u;
}

__global__ void k_bias2(const unsigned short* __restrict__ wpb, const float* __restrict__ bk,
                        const float* __restrict__ bv, float* __restrict__ bias2) {
  const int wave = threadIdx.x >> 6, lane = threadIdx.x & 63;
  const int row = blockIdx.x * 4 + wave;
  const unsigned short* wr = wpb + (size_t)row * HH;
  float s = 0.f;
#pragma unroll
  for (int ch = 0; ch < 4; ++ch) {
    const int col = ch * 256 + lane * 4;
    float4 a = *(const float4*)(bk + col);
    ushort4 u = *(const ushort4*)(wr + col);
    s += a.x * bf2f(u.x) + a.y * bf2f(u.y) + a.z * bf2f(u.z) + a.w * bf2f(u.w);
  }
#pragma unroll
  for (int off = 32; off > 0; off >>= 1) s += __shfl_down(s, off);
  if (lane == 0) bias2[row] = s - bv[row & 1023];
}

__global__ void k_scan(const float* __restrict__ lrlog, const float* __restrict__ wdlog,
                       const float* __restrict__ lbl, const float* __restrict__ blr,
                       const float* __restrict__ lbw, const float* __restrict__ bwd,
                       float* __restrict__ lr, float* __restrict__ c,
                       float* __restrict__ s, float* __restrict__ ecl) {
  const int b = blockIdx.x, t = threadIdx.x;
  __shared__ float sums[256];
  const float elr = expf(lbl[0]);
  const float ewd = expf(lbw[0]);
  const float blr0 = blr[0], bwd0 = bwd[0];
  float lw[8];
  const float* wb = wdlog + (size_t)b * LL + t * 8;
  float tot = 0.f;
#pragma unroll
  for (int i = 0; i < 8; ++i) {
    float z = wb[i] + bwd0;
    float sig = 1.f / (1.f + expf(-z));
    tot += log1pf(-ewd * sig);
    lw[i] = tot;
  }
  sums[t] = tot;
  __syncthreads();
  for (int off = 1; off < 256; off <<= 1) {
    float v = (t >= off) ? sums[t - off] : 0.f;
    __syncthreads();
    sums[t] += v;
    __syncthreads();
  }
  const float prev = (t > 0) ? sums[t - 1] : 0.f;
  const float ctot = sums[255];
  const float* lb = lrlog + (size_t)b * LL + t * 8;
#pragma unroll
  for (int i = 0; i < 8; ++i) {
    const int idx = b * LL + t * 8 + i;
    const float ci = prev + lw[i];
    c[idx] = ci;
    float zl = lb[i] + blr0;
    float lri = elr / (1.f + expf(-zl));
    lr[idx] = lri;
    s[idx] = lri * expf(ctot - ci);
  }
  if (t == 0) ecl[b] = expf(ctot);
}

// ---------------- GEMM kernels ----------------

// W2T[b][d][j] = sum_h Wp[b,d,h]*Wk[j,h] - Wv[j,d]
__global__ __launch_bounds__(512, 2) void k2_gemm_m2(const unsigned short* __restrict__ wpb,
    const unsigned short* __restrict__ wkr, const unsigned short* __restrict__ wvtn,
    unsigned short* __restrict__ w2t) {
  __shared__ Smem2<4> sm;
  const int b = blockIdx.x;
  const int mt = blockIdx.y & 7, nt = blockIdx.y >> 3;
  const int m0 = mt * 128, n0 = nt * 256;
  f32x4 acc[4][4]; acc_init2<4>(acc);
  gemm2_core<4>(
    [&](int r, int kt) { return wpb + (size_t)b * DD * HH + (size_t)(m0 + r) * HH + kt * 64; },
    [&](int r, int kt) { return wkr + (size_t)(n0 + r) * HH + kt * 64; },
    HH / 64, &sm, acc);
  epi2<4>(acc, [&](int rr, int cc, float av) {
    const size_t gi = (size_t)(m0 + rr) * DD + (n0 + cc);
    w2t[(size_t)b * DD * DD + gi] = f2bf(av + bf2f(wvtn[gi]));   // wvtn = -Wv^T
  });
}

// Q = X*WqT + bq; q2 = exp(c[m]) * Q
__global__ __launch_bounds__(512, 2) void k2_gemm_q(const unsigned short* __restrict__ xb,
    const unsigned short* __restrict__ wt, const float* __restrict__ bias,
    const float* __restrict__ c, unsigned short* __restrict__ outb,
    unsigned short* __restrict__ q2b) {
  __shared__ Smem2<8> sm;
  const int mt = blockIdx.x * 8 + (blockIdx.y & 7);  // XCD x owns batch-x rows
  const int nt = blockIdx.y >> 3;
  const int m0 = mt * 256, n0 = nt * 256;
  f32x4 acc[8][4]; acc_init2<8>(acc);
  gemm2_core<8>(
    [&](int r, int kt) { return xb + (size_t)(m0 + r) * DD + kt * 64; },
    [&](int r, int kt) { return wt + (size_t)(n0 + r) * DD + kt * 64; },
    DD / 64, &sm, acc);
  epi2<8>(acc, [&](int rr, int cc, float av) {
    const int row = m0 + rr, col = n0 + cc;
    const float v = av + bias[col];
    outb[(size_t)row * HH + col] = f2bf(v);
    q2b[(size_t)row * HH + col] = f2bf(v * __expf(c[row]));
  });
}

__global__ __launch_bounds__(512, 2) void k2_gemm_k(const unsigned short* __restrict__ xb,
    const unsigned short* __restrict__ wt, const float* __restrict__ bias,
    const float* __restrict__ s, unsigned short* __restrict__ kb,
    unsigned short* __restrict__ k2t) {
  __shared__ Smem2<8> sm;
  const int mt = blockIdx.x * 8 + (blockIdx.y & 7);
  const int nt = blockIdx.y >> 3;
  const int m0 = mt * 256, n0 = nt * 256;
  f32x4 acc[8][4]; acc_init2<8>(acc);
  gemm2_core<8>(
    [&](int r, int kt) { return xb + (size_t)(m0 + r) * DD + kt * 64; },
    [&](int r, int kt) { return wt + (size_t)(n0 + r) * DD + kt * 64; },
    DD / 64, &sm, acc);
  const int lane = threadIdx.x & 63, wave = threadIdx.x >> 6;
  const int mwr = (wave >> 2) * 128, nwr = (wave & 3) * 64;
#pragma unroll
  for (int i = 0; i < 8; ++i)
#pragma unroll
    for (int j = 0; j < 4; ++j) {
      const int col = n0 + nwr + j*16 + (lane & 15);
      const float bias_c = bias[col];
      const int row0 = m0 + mwr + i*16 + ((lane >> 4) << 2);
      const int b = row0 >> 11, ml0 = row0 & 2047;
      unsigned short tmp[4];
#pragma unroll
      for (int jj = 0; jj < 4; ++jj) {
        float v = acc[i][j][jj] + bias_c;
        kb[(size_t)(row0 + jj) * HH + col] = f2bf(v);
        tmp[jj] = f2bf(v * s[row0 + jj]);
      }
      uint2 u;
      u.x = (unsigned)tmp[0] | ((unsigned)tmp[1] << 16);
      u.y = (unsigned)tmp[2] | ((unsigned)tmp[3] << 16);
      *(uint2*)&k2t[((size_t)b * HH + col) * LL + ml0] = u;
    }
}

// U = X*W2T + bias2, stored transposed ut[b][d][l]
__global__ __launch_bounds__(512, 2) void k2_gemm_u(const unsigned short* __restrict__ xb,
    const unsigned short* __restrict__ w2t, const float* __restrict__ bias2,
    unsigned short* __restrict__ ut) {
  __shared__ Smem2<8> sm;
  const int b = blockIdx.x;                          // mt>>3 == blockIdx.x
  const int mt = blockIdx.x * 8 + (blockIdx.y & 7);
  const int nt = blockIdx.y >> 3;
  const int m0 = mt * 256, n0 = nt * 256;
  f32x4 acc[8][4]; acc_init2<8>(acc);
  gemm2_core<8>(
    [&](int r, int kt) { return xb + (size_t)(m0 + r) * DD + kt * 64; },
    [&](int r, int kt) { return w2t + (size_t)b * DD * DD + (size_t)(n0 + r) * DD + kt * 64; },
    DD / 64, &sm, acc);
  const int lane = threadIdx.x & 63, wave = threadIdx.x >> 6;
  const int mwr = (wave >> 2) * 128, nwr = (wave & 3) * 64;
#pragma unroll
  for (int i = 0; i < 8; ++i)
#pragma unroll
    for (int j = 0; j < 4; ++j) {
      const int col = n0 + nwr + j*16 + (lane & 15);
      const float b2c = bias2[b * DD + col];
      const int row0 = m0 + mwr + i*16 + ((lane >> 4) << 2);
      const int ml0 = row0 & 2047;
      unsigned short tmp[4];
#pragma unroll
      for (int jj = 0; jj < 4; ++jj) tmp[jj] = f2bf(acc[i][j][jj] + b2c);
      uint2 u;
      u.x = (unsigned)tmp[0] | ((unsigned)tmp[1] << 16);
      u.y = (unsigned)tmp[2] | ((unsigned)tmp[3] << 16);
      *(uint2*)&ut[((size_t)b * DD + col) * LL + ml0] = u;
    }
}

// pb[m,l] = -lr[l]*exp(c[m]-c[l]) * (Q K^T)[m,l]  (old core; triangular tiles)
__global__ __launch_bounds__(256) void k_gemm_p(const unsigned short* __restrict__ qb,
    const unsigned short* __restrict__ kb, const float* __restrict__ lr,
    const float* __restrict__ c, unsigned short* __restrict__ pb) {
  const int b = blockIdx.z;
  const int i = blockIdx.x;                    // 0..135
  const int t = (i & 7) * 17 + (i >> 3);       // 136 = 8 * 17
  int mt = (int)((sqrtf(8.0f * (float)t + 1.0f) - 1.0f) * 0.5f);
  while ((mt + 1) * (mt + 2) / 2 <= t) ++mt;
  while (mt * (mt + 1) / 2 > t) --mt;
  const int nt = t - mt * (mt + 1) / 2;
  __shared__ Smem sm;
  f32x4 acc[4][4]; acc_init(acc);
  const int base = b * LL;
  const int m0g = base + mt * TM, n0g = base + nt * TN;
  gemm_core(qb, HH, kb, HH, m0g, n0g, HH / BK, &sm, acc);

  const int lane = threadIdx.x & 63, wave = threadIdx.x >> 6;
  const int mw = (wave >> 1) * 64, nw = (wave & 1) * 64;
  if (nt != mt) {
    const float cref = c[base + mt * TM];
    float er[4][4], fc[4];
#pragma unroll
    for (int mi = 0; mi < 4; ++mi)
#pragma unroll
      for (int j = 0; j < 4; ++j) {
        const int m = mt * TM + mw + mi*16 + ((lane >> 4) << 2) + j;
        er[mi][j] = __expf(c[base + m] - cref);
      }
#pragma unroll
    for (int ni = 0; ni < 4; ++ni) {
      const int l = nt * TN + nw + ni*16 + (lane & 15);
      fc[ni] = lr[base + l] * __expf(cref - c[base + l]);
    }
#pragma unroll
    for (int mi = 0; mi < 4; ++mi)
#pragma unroll
      for (int ni = 0; ni < 4; ++ni) {
        const int l = nt * TN + nw + ni*16 + (lane & 15);
        const int row0 = mt * TM + mw + mi*16 + ((lane >> 4) << 2);
#pragma unroll
        for (int j = 0; j < 4; ++j) {
          const float v = -acc[mi][ni][j] * er[mi][j] * fc[ni];
          pb[((size_t)base + row0 + j) * LL + l] = f2bf(v);
        }
      }
  } else {
    epilogue_loop(acc, [&](int rr, int cc, float av) {
      const int m = mt * TM + rr, l = nt * TN + cc;
      float v = 0.f;
      if (l <= m) v = -av * lr[base + l] * __expf(c[base + m] - c[base + l]);
      pb[((size_t)base + m) * LL + l] = f2bf(v);
    });
  }
}

// y = pb*U + q2*Wp^T, fused into one pipelined K-sequence (no inter-call drain).
// Grid (8,64): x = batch (XCD), y: mt = 15-(y&15) heavy-first, nt = y>>4.
__global__ __launch_bounds__(512, 2) void k2_gemm_y(const unsigned short* __restrict__ pb,
    const unsigned short* __restrict__ ut, const unsigned short* __restrict__ q2b,
    const unsigned short* __restrict__ wpb, float* __restrict__ out) {
  __shared__ Smem2<4> sm;
  const int b = blockIdx.x;
  const int mt = 15 - (blockIdx.y & 15);
  const int nt = blockIdx.y >> 4;
  const int m0 = mt * 128, n0 = nt * 256;
  const int NK1 = (mt + 1) * 2;                 // pb cols l < (mt+1)*128
  f32x4 acc[4][4]; acc_init2<4>(acc);
  gemm2_core<4>(
    [&](int r, int kt) {
      return (kt < NK1) ? pb + (size_t)b * LL * LL + (size_t)(m0 + r) * LL + kt * 64
                        : q2b + ((size_t)b * LL + m0 + r) * HH + (kt - NK1) * 64;
    },
    [&](int r, int kt) {
      return (kt < NK1) ? ut + (size_t)b * DD * LL + (size_t)(n0 + r) * LL + kt * 64
                        : wpb + (size_t)b * DD * HH + (size_t)(n0 + r) * HH + (kt - NK1) * 64;
    },
    NK1 + 16, &sm, acc);
  epi2<4>(acc, [&](int rr, int cc, float av) {
    out[((size_t)b * LL + m0 + rr) * DD + (n0 + cc)] = av;
  });
}

// W_next = -Ut * K2t^T + ecl[b]*W_prev
__global__ __launch_bounds__(512, 2) void k2_gemm_wn(const unsigned short* __restrict__ ut,
    const unsigned short* __restrict__ k2t, const float* __restrict__ hid,
    const float* __restrict__ ecl, float* __restrict__ out2) {
  __shared__ Smem2<4> sm;
  const int b = blockIdx.x;
  const int mt = blockIdx.y & 7, nt = blockIdx.y >> 3;
  const int m0 = mt * 128, n0 = nt * 256;
  f32x4 acc[4][4]; acc_init2<4>(acc);
  gemm2_core<4>(
    [&](int r, int kt) { return ut + (size_t)b * DD * LL + (size_t)(m0 + r) * LL + kt * 64; },
    [&](int r, int kt) { return k2t + (size_t)b * HH * LL + (size_t)(n0 + r) * LL + kt * 64; },
    LL / 64, &sm, acc);
  const float eclb = ecl[b];
  epi2<4>(acc, [&](int rr, int cc, float av) {
    const size_t gi = ((size_t)b * DD + (m0 + rr)) * HH + (n0 + cc);
    out2[gi] = -av + eclb * hid[gi];
  });
}

// ---------------- launcher ----------------

extern "C" void kernel_launch(void* const* d_in, const int* in_sizes, int n_in,
                              void* d_out, int out_size, void* d_ws, size_t ws_size,
                              hipStream_t stream) {
  (void)in_sizes; (void)n_in; (void)out_size; (void)ws_size;
  const float* x   = (const float*)d_in[0];
  const float* hid = (const float*)d_in[1];
  const float* lbl = (const float*)d_in[2];
  const float* wlr = (const float*)d_in[3];
  const float* blr = (const float*)d_in[4];
  const float* lbw = (const float*)d_in[5];
  const float* wwd = (const float*)d_in[6];
  const float* bwd = (const float*)d_in[7];
  const float* wq  = (const float*)d_in[8];
  const float* bq  = (const float*)d_in[9];
  const float* wk  = (const float*)d_in[10];
  const float* bk  = (const float*)d_in[11];
  const float* wv  = (const float*)d_in[12];
  const float* bv  = (const float*)d_in[13];
  float* out = (float*)d_out;

  char* w = (char*)d_ws;
  constexpr size_t SZ_XB  = (size_t)BL * DD * 2;
  constexpr size_t SZ_QB  = (size_t)BL * HH * 2;
  constexpr size_t SZ_KB  = (size_t)BL * HH * 2;
  constexpr size_t SZ_K2T = (size_t)BB * HH * LL * 2;
  constexpr size_t SZ_UT  = (size_t)BB * DD * LL * 2;
  constexpr size_t SZ_PB  = (size_t)BB * LL * LL * 2;
  constexpr size_t SZ_WT  = (size_t)DD * HH * 2;
  constexpr size_t SZ_WPB = (size_t)BB * DD * HH * 2;
  constexpr size_t SZ_V16 = (size_t)BL * 4;

  size_t off = 0;
  unsigned short* xb   = (unsigned short*)(w + off); off += SZ_XB;
  unsigned short* qb   = (unsigned short*)(w + off); off += SZ_QB;
  unsigned short* kb   = (unsigned short*)(w + off); off += SZ_KB;
  unsigned short* k2t  = (unsigned short*)(w + off); off += SZ_K2T;
  unsigned short* ut   = (unsigned short*)(w + off); off += SZ_UT;
  unsigned short* pb   = (unsigned short*)(w + off); off += SZ_PB;
  unsigned short* wqt  = (unsigned short*)(w + off); off += SZ_WT;
  unsigned short* wkt  = (unsigned short*)(w + off); off += SZ_WT;
  unsigned short* wvtn = (unsigned short*)(w + off); off += SZ_WT;
  unsigned short* wpb  = (unsigned short*)(w + off); off += SZ_WPB;
  float* lrlog = (float*)(w + off); off += SZ_V16;
  float* wdlog = (float*)(w + off); off += SZ_V16;
  float* lr    = (float*)(w + off); off += SZ_V16;
  float* c     = (float*)(w + off); off += SZ_V16;
  float* s     = (float*)(w + off); off += SZ_V16;
  float* ecl   = (float*)(w + off); off += 256;
  float* bias2 = (float*)(w + off); off += (size_t)BB * DD * 4;

  // w2t (16.8 MB) + wkr (2 MB) alias the pb region: dead before k_gemm_p writes pb.
  unsigned short* w2t = pb;
  unsigned short* wkr = pb + (size_t)BB * DD * DD;

  // q2 scratch lives in d_out's W_next region; overwritten by k2_gemm_wn afterwards.
  unsigned short* q2b = (unsigned short*)(out + (size_t)BL * DD);
  float* out2 = out + (size_t)BL * DD;

  k_prep_x<<<dim3(BL / 4), 256, 0, stream>>>(x, wlr, wwd, xb, lrlog, wdlog);
  k_prep_w<<<dim3(4096, 1, 4), 256, 0, stream>>>(wq, wk, wv, wqt, wkt, wvtn, wkr);
  k_prep_h<<<dim3((unsigned)((size_t)BB * DD * HH / 1024)), 256, 0, stream>>>(hid, wpb);
  k_scan<<<dim3(BB), 256, 0, stream>>>(lrlog, wdlog, lbl, blr, lbw, bwd, lr, c, s, ecl);
  k_bias2<<<dim3(BB * DD / 4), 256, 0, stream>>>(wpb, bk, bv, bias2);

  k2_gemm_m2<<<dim3(8, 32), 512, 0, stream>>>(wpb, wkr, wvtn, w2t);
  k2_gemm_q<<<dim3(8, 32), 512, 0, stream>>>(xb, wqt, bq, c, qb, q2b);
  k2_gemm_k<<<dim3(8, 32), 512, 0, stream>>>(xb, wkt, bk, s, kb, k2t);
  k2_gemm_u<<<dim3(8, 32), 512, 0, stream>>>(xb, w2t, bias2, ut);
  k_gemm_p<<<dim3(136, 1, BB), 256, 0, stream>>>(qb, kb, lr, c, pb);
  k2_gemm_y<<<dim3(8, 64), 512, 0, stream>>>(pb, ut, q2b, wpb, out);
  k2_gemm_wn<<<dim3(8, 32), 512, 0, stream>>>(ut, k2t, hid, ecl, out2);
}

// Round 3
// 615.921 us; speedup vs baseline: 1.1348x; 1.0203x over previous
//
#include <hip/hip_runtime.h>
#include <stdint.h>

#define BB 8
#define LL 2048
#define DD 1024
#define HH 1024
#define BL (BB*LL)   // 16384

typedef __attribute__((ext_vector_type(8))) short short8;
typedef __attribute__((ext_vector_type(4))) float f32x4;

__device__ __forceinline__ unsigned short f2bf(float f) {
  unsigned int x = __float_as_uint(f);
  unsigned int r = (x + 0x7fffu + ((x >> 16) & 1u)) >> 16;
  return (unsigned short)r;
}
__device__ __forceinline__ float bf2f(unsigned short u) {
  return __uint_as_float(((unsigned int)u) << 16);
}

__device__ __forceinline__ void stage16(const unsigned short* g, unsigned short* l) {
  __builtin_amdgcn_global_load_lds((const __attribute__((address_space(1))) void*)g,
                                   (__attribute__((address_space(3))) void*)l,
                                   16, 0, 0);
}

// counted s_waitcnt immediates (compile-time constant strings)
template<int N> struct WaitVm;
#define WVM(N) template<> struct WaitVm<N> { \
  static __device__ __forceinline__ void w() { \
    asm volatile("s_waitcnt vmcnt(" #N ")" ::: "memory"); } };
WVM(0) WVM(6) WVM(8) WVM(12)
#undef WVM

// ================= counted-vmcnt pipelined core =================
// 512 threads = 8 waves (2M x 4N). BM = MI*32 (MI=8 -> 256, MI=4 -> 128),
// BN = 256, BK = 64. PD = prefetch depth (tiles in flight), NB = PD+1 LDS
// buffers. Per iteration:
//   STAGE(tile kt+PD)                  // LPW loads/wave into buffer (kt+PD)%NB
//   s_waitcnt vmcnt(PD*LPW)            // drains tile kt ONLY (T4: never 0)
//   s_barrier                          // all waves' tile-kt loads are in LDS
//   COMPUTE(kt)                        // tile kt+1..kt+PD loads fly under this
//   s_barrier                          // protect buffer before next overwrite
// Tile kt's loads thus get PD full iterations of latency cover. Trailing
// barrier: next iter's STAGE writes buffer (kt)%NB == the one just computed.
// XOR-swizzled LDS (SQ_LDS_BANK_CONFLICT == 0 verified round 3 prev session).
template<int MI, int PD>
struct __align__(16) Smem3 {
  unsigned short a[PD+1][MI*2048];   // BM x 64 per buffer
  unsigned short b[PD+1][16384];     // 256 x 64 per buffer
};

template<int MI>
__device__ __forceinline__ void acc_init2(f32x4 (&acc)[MI][4]) {
#pragma unroll
  for (int i = 0; i < MI; ++i)
#pragma unroll
    for (int j = 0; j < 4; ++j)
      acc[i][j] = (f32x4){0.f, 0.f, 0.f, 0.f};
}

template<int MI, int PD, class FA, class FB>
__device__ __forceinline__ void gemm3_core(FA srcA, FB srcB, int NK,
                                           Smem3<MI,PD>* sm, f32x4 (&acc)[MI][4]) {
  constexpr int NB  = PD + 1;
  constexpr int APW = MI / 2;          // A chunks (loads) per wave per stage
  constexpr int LPW = APW + 4;         // total loads per wave per stage
  const int lane = threadIdx.x & 63;
  const int wave = threadIdx.x >> 6;           // 0..7
  const int srow = lane >> 3;                  // 0..7
  const int scol = ((lane & 7) ^ srow) * 8;    // swizzled source column
  const int fk = (lane >> 4) * 8;
  const int fr = lane & 15;
  const int fx = fr & 7;
  const int mwr = (wave >> 2) * (MI * 16);     // wave row base
  const int nwr = (wave & 3) * 64;             // wave col base

  auto STAGE = [&](int p, int kt) {
#pragma unroll
    for (int r = 0; r < APW; ++r) {
      const int chunk = wave * APW + r;        // wave-uniform
      stage16(srcA(chunk * 8 + srow, kt) + scol, &sm->a[p][chunk * 512]);
    }
#pragma unroll
    for (int r = 0; r < 4; ++r) {
      const int chunk = wave * 4 + r;
      stage16(srcB(chunk * 8 + srow, kt) + scol, &sm->b[p][chunk * 512]);
    }
  };
  auto COMPUTE = [&](int p) {
    const unsigned short* pa  = sm->a[p];
    const unsigned short* pbp = sm->b[p];
#pragma unroll
    for (int kk = 0; kk < 64; kk += 32) {
      const int kc = ((((kk + fk) >> 3) ^ fx) << 3);
      short8 af[MI], bfv[4];
#pragma unroll
      for (int i = 0; i < MI; ++i)
        af[i] = *(const short8*)&pa[(mwr + i*16 + fr) * 64 + kc];
#pragma unroll
      for (int j = 0; j < 4; ++j)
        bfv[j] = *(const short8*)&pbp[(nwr + j*16 + fr) * 64 + kc];
#pragma unroll
      for (int i = 0; i < MI; ++i)
#pragma unroll
        for (int j = 0; j < 4; ++j)
          acc[i][j] = __builtin_amdgcn_mfma_f32_16x16x32_bf16(af[i], bfv[j], acc[i][j], 0, 0, 0);
    }
  };

#pragma unroll
  for (int d = 0; d < PD; ++d) STAGE(d, d);    // prologue: tiles 0..PD-1
  int pc = 0;                                  // compute buffer
  int ps = PD % NB;                            // stage buffer
  for (int kt = 0; kt < NK; ++kt) {
    if (kt + PD < NK) {
      STAGE(ps, kt + PD);
      ps = (ps + 1 == NB) ? 0 : ps + 1;
      WaitVm<PD * LPW>::w();                   // tile kt landed; kt+1..kt+PD in flight
    } else if (PD == 2 && kt + PD == NK) {
      WaitVm<LPW>::w();                        // one tile still in flight
    } else {
      WaitVm<0>::w();                          // last tile
    }
    __builtin_amdgcn_s_barrier();
    __builtin_amdgcn_sched_barrier(0);
    COMPUTE(pc);
    pc = (pc + 1 == NB) ? 0 : pc + 1;
    __builtin_amdgcn_s_barrier();
  }
}

// per-element epilogue: body(rr, cc, av), rr/cc within the BM x 256 tile
template<int MI, typename F>
__device__ __forceinline__ void epi2(const f32x4 (&acc)[MI][4], F body) {
  const int lane = threadIdx.x & 63;
  const int wave = threadIdx.x >> 6;
  const int mwr = (wave >> 2) * (MI * 16), nwr = (wave & 3) * 64;
#pragma unroll
  for (int i = 0; i < MI; ++i)
#pragma unroll
    for (int j = 0; j < 4; ++j)
#pragma unroll
      for (int jj = 0; jj < 4; ++jj) {
        const int rr = mwr + i * 16 + ((lane >> 4) << 2) + jj;
        const int cc = nwr + j * 16 + (lane & 15);
        body(rr, cc, acc[i][j][jj]);
      }
}

// ---------------- prep kernels ----------------

__global__ void k_prep_x(const float* __restrict__ x, const float* __restrict__ wlr,
                         const float* __restrict__ wwd, unsigned short* __restrict__ xb,
                         float* __restrict__ lrlog, float* __restrict__ wdlog) {
  const int wave = threadIdx.x >> 6, lane = threadIdx.x & 63;
  const int row = blockIdx.x * 4 + wave;
  const float* xr = x + (size_t)row * DD;
  float s1 = 0.f, s2 = 0.f;
#pragma unroll
  for (int ch = 0; ch < 4; ++ch) {
    const int col = ch * 256 + lane * 4;
    float4 v = *(const float4*)(xr + col);
    float4 a = *(const float4*)(wlr + col);
    float4 b = *(const float4*)(wwd + col);
    s1 += v.x*a.x + v.y*a.y + v.z*a.z + v.w*a.w;
    s2 += v.x*b.x + v.y*b.y + v.z*b.z + v.w*b.w;
    uint2 u;
    u.x = (unsigned)f2bf(v.x) | ((unsigned)f2bf(v.y) << 16);
    u.y = (unsigned)f2bf(v.z) | ((unsigned)f2bf(v.w) << 16);
    *(uint2*)(xb + (size_t)row * DD + col) = u;
  }
#pragma unroll
  for (int off = 32; off > 0; off >>= 1) {
    s1 += __shfl_down(s1, off);
    s2 += __shfl_down(s2, off);
  }
  if (lane == 0) { lrlog[row] = s1; wdlog[row] = s2; }
}

__global__ void k_prep_w(const float* __restrict__ wq, const float* __restrict__ wk,
                         const float* __restrict__ wv, unsigned short* __restrict__ wqt,
                         unsigned short* __restrict__ wkt, unsigned short* __restrict__ wvtn,
                         unsigned short* __restrict__ wkr) {
  const int idx = blockIdx.x * 256 + threadIdx.x;
  if (blockIdx.z == 3) { wkr[idx] = f2bf(wk[idx]); return; }
  const int k = idx >> 10, n = idx & 1023;
  const float* src = (blockIdx.z == 0) ? wq : (blockIdx.z == 1) ? wk : wv;
  unsigned short* dst = (blockIdx.z == 0) ? wqt : (blockIdx.z == 1) ? wkt : wvtn;
  float v = src[(size_t)k * 1024 + n];
  if (blockIdx.z == 2) v = -v;
  dst[(size_t)n * 1024 + k] = f2bf(v);
}

__global__ void k_prep_h(const float* __restrict__ hid, unsigned short* __restrict__ wpb) {
  const size_t i = ((size_t)blockIdx.x * 256 + threadIdx.x) * 4;
  float4 v = *(const float4*)(hid + i);
  uint2 u;
  u.x = (unsigned)f2bf(v.x) | ((unsigned)f2bf(v.y) << 16);
  u.y = (unsigned)f2bf(v.z) | ((unsigned)f2bf(v.w) << 16);
  *(uint2*)(wpb + i) = u;
}

__global__ void k_bias2(const unsigned short* __restrict__ wpb, const float* __restrict__ bk,
                        const float* __restrict__ bv, float* __restrict__ bias2) {
  const int wave = threadIdx.x >> 6, lane = threadIdx.x & 63;
  const int row = blockIdx.x * 4 + wave;
  const unsigned short* wr = wpb + (size_t)row * HH;
  float s = 0.f;
#pragma unroll
  for (int ch = 0; ch < 4; ++ch) {
    const int col = ch * 256 + lane * 4;
    float4 a = *(const float4*)(bk + col);
    ushort4 u = *(const ushort4*)(wr + col);
    s += a.x * bf2f(u.x) + a.y * bf2f(u.y) + a.z * bf2f(u.z) + a.w * bf2f(u.w);
  }
#pragma unroll
  for (int off = 32; off > 0; off >>= 1) s += __shfl_down(s, off);
  if (lane == 0) bias2[row] = s - bv[row & 1023];
}

__global__ void k_scan(const float* __restrict__ lrlog, const float* __restrict__ wdlog,
                       const float* __restrict__ lbl, const float* __restrict__ blr,
                       const float* __restrict__ lbw, const float* __restrict__ bwd,
                       float* __restrict__ lr, float* __restrict__ c,
                       float* __restrict__ s, float* __restrict__ ecl) {
  const int b = blockIdx.x, t = threadIdx.x;
  __shared__ float sums[256];
  const float elr = expf(lbl[0]);
  const float ewd = expf(lbw[0]);
  const float blr0 = blr[0], bwd0 = bwd[0];
  float lw[8];
  const float* wb = wdlog + (size_t)b * LL + t * 8;
  float tot = 0.f;
#pragma unroll
  for (int i = 0; i < 8; ++i) {
    float z = wb[i] + bwd0;
    float sig = 1.f / (1.f + expf(-z));
    tot += log1pf(-ewd * sig);
    lw[i] = tot;
  }
  sums[t] = tot;
  __syncthreads();
  for (int off = 1; off < 256; off <<= 1) {
    float v = (t >= off) ? sums[t - off] : 0.f;
    __syncthreads();
    sums[t] += v;
    __syncthreads();
  }
  const float prev = (t > 0) ? sums[t - 1] : 0.f;
  const float ctot = sums[255];
  const float* lb = lrlog + (size_t)b * LL + t * 8;
#pragma unroll
  for (int i = 0; i < 8; ++i) {
    const int idx = b * LL + t * 8 + i;
    const float ci = prev + lw[i];
    c[idx] = ci;
    float zl = lb[i] + blr0;
    float lri = elr / (1.f + expf(-zl));
    lr[idx] = lri;
    s[idx] = lri * expf(ctot - ci);
  }
  if (t == 0) ecl[b] = expf(ctot);
}

// ---------------- GEMM kernels ----------------

// W2T[b][d][j] = sum_h Wp[b,d,h]*Wk[j,h] - Wv[j,d]
__global__ __launch_bounds__(512, 2) void k3_gemm_m2(const unsigned short* __restrict__ wpb,
    const unsigned short* __restrict__ wkr, const unsigned short* __restrict__ wvtn,
    unsigned short* __restrict__ w2t) {
  __shared__ Smem3<4,2> sm;
  const int b = blockIdx.x;
  const int mt = blockIdx.y & 7, nt = blockIdx.y >> 3;
  const int m0 = mt * 128, n0 = nt * 256;
  f32x4 acc[4][4]; acc_init2<4>(acc);
  gemm3_core<4,2>(
    [&](int r, int kt) { return wpb + (size_t)b * DD * HH + (size_t)(m0 + r) * HH + kt * 64; },
    [&](int r, int kt) { return wkr + (size_t)(n0 + r) * HH + kt * 64; },
    HH / 64, &sm, acc);
  epi2<4>(acc, [&](int rr, int cc, float av) {
    const size_t gi = (size_t)(m0 + rr) * DD + (n0 + cc);
    w2t[(size_t)b * DD * DD + gi] = f2bf(av + bf2f(wvtn[gi]));   // wvtn = -Wv^T
  });
}

// Q = X*WqT + bq; q2 = exp(c[m]) * Q
__global__ __launch_bounds__(512, 2) void k3_gemm_q(const unsigned short* __restrict__ xb,
    const unsigned short* __restrict__ wt, const float* __restrict__ bias,
    const float* __restrict__ c, unsigned short* __restrict__ outb,
    unsigned short* __restrict__ q2b) {
  __shared__ Smem3<8,1> sm;
  const int mt = blockIdx.x * 8 + (blockIdx.y & 7);  // XCD x owns batch-x rows
  const int nt = blockIdx.y >> 3;
  const int m0 = mt * 256, n0 = nt * 256;
  f32x4 acc[8][4]; acc_init2<8>(acc);
  gemm3_core<8,1>(
    [&](int r, int kt) { return xb + (size_t)(m0 + r) * DD + kt * 64; },
    [&](int r, int kt) { return wt + (size_t)(n0 + r) * DD + kt * 64; },
    DD / 64, &sm, acc);
  epi2<8>(acc, [&](int rr, int cc, float av) {
    const int row = m0 + rr, col = n0 + cc;
    const float v = av + bias[col];
    outb[(size_t)row * HH + col] = f2bf(v);
    q2b[(size_t)row * HH + col] = f2bf(v * __expf(c[row]));
  });
}

__global__ __launch_bounds__(512, 2) void k3_gemm_k(const unsigned short* __restrict__ xb,
    const unsigned short* __restrict__ wt, const float* __restrict__ bias,
    const float* __restrict__ s, unsigned short* __restrict__ kb,
    unsigned short* __restrict__ k2t) {
  __shared__ Smem3<8,1> sm;
  const int mt = blockIdx.x * 8 + (blockIdx.y & 7);
  const int nt = blockIdx.y >> 3;
  const int m0 = mt * 256, n0 = nt * 256;
  f32x4 acc[8][4]; acc_init2<8>(acc);
  gemm3_core<8,1>(
    [&](int r, int kt) { return xb + (size_t)(m0 + r) * DD + kt * 64; },
    [&](int r, int kt) { return wt + (size_t)(n0 + r) * DD + kt * 64; },
    DD / 64, &sm, acc);
  const int lane = threadIdx.x & 63, wave = threadIdx.x >> 6;
  const int mwr = (wave >> 2) * 128, nwr = (wave & 3) * 64;
#pragma unroll
  for (int i = 0; i < 8; ++i)
#pragma unroll
    for (int j = 0; j < 4; ++j) {
      const int col = n0 + nwr + j*16 + (lane & 15);
      const float bias_c = bias[col];
      const int row0 = m0 + mwr + i*16 + ((lane >> 4) << 2);
      const int b = row0 >> 11, ml0 = row0 & 2047;
      unsigned short tmp[4];
#pragma unroll
      for (int jj = 0; jj < 4; ++jj) {
        float v = acc[i][j][jj] + bias_c;
        kb[(size_t)(row0 + jj) * HH + col] = f2bf(v);
        tmp[jj] = f2bf(v * s[row0 + jj]);
      }
      uint2 u;
      u.x = (unsigned)tmp[0] | ((unsigned)tmp[1] << 16);
      u.y = (unsigned)tmp[2] | ((unsigned)tmp[3] << 16);
      *(uint2*)&k2t[((size_t)b * HH + col) * LL + ml0] = u;
    }
}

// U = X*W2T + bias2, stored transposed ut[b][d][l]
__global__ __launch_bounds__(512, 2) void k3_gemm_u(const unsigned short* __restrict__ xb,
    const unsigned short* __restrict__ w2t, const float* __restrict__ bias2,
    unsigned short* __restrict__ ut) {
  __shared__ Smem3<8,1> sm;
  const int b = blockIdx.x;                          // mt>>3 == blockIdx.x
  const int mt = blockIdx.x * 8 + (blockIdx.y & 7);
  const int nt = blockIdx.y >> 3;
  const int m0 = mt * 256, n0 = nt * 256;
  f32x4 acc[8][4]; acc_init2<8>(acc);
  gemm3_core<8,1>(
    [&](int r, int kt) { return xb + (size_t)(m0 + r) * DD + kt * 64; },
    [&](int r, int kt) { return w2t + (size_t)b * DD * DD + (size_t)(n0 + r) * DD + kt * 64; },
    DD / 64, &sm, acc);
  const int lane = threadIdx.x & 63, wave = threadIdx.x >> 6;
  const int mwr = (wave >> 2) * 128, nwr = (wave & 3) * 64;
#pragma unroll
  for (int i = 0; i < 8; ++i)
#pragma unroll
    for (int j = 0; j < 4; ++j) {
      const int col = n0 + nwr + j*16 + (lane & 15);
      const float b2c = bias2[b * DD + col];
      const int row0 = m0 + mwr + i*16 + ((lane >> 4) << 2);
      const int ml0 = row0 & 2047;
      unsigned short tmp[4];
#pragma unroll
      for (int jj = 0; jj < 4; ++jj) tmp[jj] = f2bf(acc[i][j][jj] + b2c);
      uint2 u;
      u.x = (unsigned)tmp[0] | ((unsigned)tmp[1] << 16);
      u.y = (unsigned)tmp[2] | ((unsigned)tmp[3] << 16);
      *(uint2*)&ut[((size_t)b * DD + col) * LL + ml0] = u;
    }
}

// pb[m,l] = -lr[l]*exp(c[m]-c[l]) * (Q K^T)[m,l] for l<=m, else 0.
// BM=128 x BN=256 tiles covering the lower triangle: per batch, 72 tiles
// (mt 0..15, nt2 < ceil((mt+1)/2)). Direct decay form everywhere: both exp
// args <= 0 (c monotone decreasing), so no overflow; masked above diagonal.
// Coverage written [0, ceil((mt+1)/2)*256) >= y's read range [0,(mt+1)*128).
__global__ __launch_bounds__(512, 2) void k3_gemm_p(const unsigned short* __restrict__ qb,
    const unsigned short* __restrict__ kb, const float* __restrict__ lr,
    const float* __restrict__ c, unsigned short* __restrict__ pb) {
  __shared__ Smem3<4,2> sm;
  const int b = blockIdx.x;                    // XCD = batch (L2 locality)
  const int t = blockIdx.y;                    // 0..71
  // pair-group r holds mt in {2r, 2r+1}, each with r+1 column tiles.
  int r = (int)((sqrtf(4.f * (float)t + 1.f) - 1.f) * 0.5f);
  while ((r + 1) * (r + 2) <= t) ++r;
  while (r * (r + 1) > t) --r;
  const int u = t - r * (r + 1);               // 0..2r+1
  const int mt = 2 * r + (u > r ? 1 : 0);
  const int nt2 = (u > r) ? (u - r - 1) : u;
  const int base = b * LL;
  const int m0 = mt * 128, n0 = nt2 * 256;
  f32x4 acc[4][4]; acc_init2<4>(acc);
  gemm3_core<4,2>(
    [&](int rr, int kt) { return qb + (size_t)(base + m0 + rr) * HH + kt * 64; },
    [&](int rr, int kt) { return kb + (size_t)(base + n0 + rr) * HH + kt * 64; },
    HH / 64, &sm, acc);
  epi2<4>(acc, [&](int rr, int cc, float av) {
    const int m = m0 + rr, l = n0 + cc;
    float v = 0.f;
    if (l <= m) v = -av * lr[base + l] * __expf(c[base + m] - c[base + l]);
    pb[((size_t)base + m) * LL + l] = f2bf(v);
  });
}

// y = pb*U + q2*Wp^T, fused into one pipelined K-sequence (no inter-call drain).
// Grid (8,64): x = batch (XCD), y: mt = 15-(y&15) heavy-first, nt = y>>4.
__global__ __launch_bounds__(512, 2) void k3_gemm_y(const unsigned short* __restrict__ pb,
    const unsigned short* __restrict__ ut, const unsigned short* __restrict__ q2b,
    const unsigned short* __restrict__ wpb, float* __restrict__ out) {
  __shared__ Smem3<4,2> sm;
  const int b = blockIdx.x;
  const int mt = 15 - (blockIdx.y & 15);
  const int nt = blockIdx.y >> 4;
  const int m0 = mt * 128, n0 = nt * 256;
  const int NK1 = (mt + 1) * 2;                 // pb cols l < (mt+1)*128
  f32x4 acc[4][4]; acc_init2<4>(acc);
  gemm3_core<4,2>(
    [&](int r, int kt) {
      return (kt < NK1) ? pb + (size_t)b * LL * LL + (size_t)(m0 + r) * LL + kt * 64
                        : q2b + ((size_t)b * LL + m0 + r) * HH + (kt - NK1) * 64;
    },
    [&](int r, int kt) {
      return (kt < NK1) ? ut + (size_t)b * DD * LL + (size_t)(n0 + r) * LL + kt * 64
                        : wpb + (size_t)b * DD * HH + (size_t)(n0 + r) * HH + (kt - NK1) * 64;
    },
    NK1 + 16, &sm, acc);
  epi2<4>(acc, [&](int rr, int cc, float av) {
    out[((size_t)b * LL + m0 + rr) * DD + (n0 + cc)] = av;
  });
}

// W_next = -Ut * K2t^T + ecl[b]*W_prev
__global__ __launch_bounds__(512, 2) void k3_gemm_wn(const unsigned short* __restrict__ ut,
    const unsigned short* __restrict__ k2t, const float* __restrict__ hid,
    const float* __restrict__ ecl, float* __restrict__ out2) {
  __shared__ Smem3<4,2> sm;
  const int b = blockIdx.x;
  const int mt = blockIdx.y & 7, nt = blockIdx.y >> 3;
  const int m0 = mt * 128, n0 = nt * 256;
  f32x4 acc[4][4]; acc_init2<4>(acc);
  gemm3_core<4,2>(
    [&](int r, int kt) { return ut + (size_t)b * DD * LL + (size_t)(m0 + r) * LL + kt * 64; },
    [&](int r, int kt) { return k2t + (size_t)b * HH * LL + (size_t)(n0 + r) * LL + kt * 64; },
    LL / 64, &sm, acc);
  const float eclb = ecl[b];
  epi2<4>(acc, [&](int rr, int cc, float av) {
    const size_t gi = ((size_t)b * DD + (m0 + rr)) * HH + (n0 + cc);
    out2[gi] = -av + eclb * hid[gi];
  });
}

// ---------------- launcher ----------------

extern "C" void kernel_launch(void* const* d_in, const int* in_sizes, int n_in,
                              void* d_out, int out_size, void* d_ws, size_t ws_size,
                              hipStream_t stream) {
  (void)in_sizes; (void)n_in; (void)out_size; (void)ws_size;
  const float* x   = (const float*)d_in[0];
  const float* hid = (const float*)d_in[1];
  const float* lbl = (const float*)d_in[2];
  const float* wlr = (const float*)d_in[3];
  const float* blr = (const float*)d_in[4];
  const float* lbw = (const float*)d_in[5];
  const float* wwd = (const float*)d_in[6];
  const float* bwd = (const float*)d_in[7];
  const float* wq  = (const float*)d_in[8];
  const float* bq  = (const float*)d_in[9];
  const float* wk  = (const float*)d_in[10];
  const float* bk  = (const float*)d_in[11];
  const float* wv  = (const float*)d_in[12];
  const float* bv  = (const float*)d_in[13];
  float* out = (float*)d_out;

  char* w = (char*)d_ws;
  constexpr size_t SZ_XB  = (size_t)BL * DD * 2;
  constexpr size_t SZ_QB  = (size_t)BL * HH * 2;
  constexpr size_t SZ_KB  = (size_t)BL * HH * 2;
  constexpr size_t SZ_K2T = (size_t)BB * HH * LL * 2;
  constexpr size_t SZ_UT  = (size_t)BB * DD * LL * 2;
  constexpr size_t SZ_PB  = (size_t)BB * LL * LL * 2;
  constexpr size_t SZ_WT  = (size_t)DD * HH * 2;
  constexpr size_t SZ_WPB = (size_t)BB * DD * HH * 2;
  constexpr size_t SZ_V16 = (size_t)BL * 4;

  size_t off = 0;
  unsigned short* xb   = (unsigned short*)(w + off); off += SZ_XB;
  unsigned short* qb   = (unsigned short*)(w + off); off += SZ_QB;
  unsigned short* kb   = (unsigned short*)(w + off); off += SZ_KB;
  unsigned short* k2t  = (unsigned short*)(w + off); off += SZ_K2T;
  unsigned short* ut   = (unsigned short*)(w + off); off += SZ_UT;
  unsigned short* pb   = (unsigned short*)(w + off); off += SZ_PB;
  unsigned short* wqt  = (unsigned short*)(w + off); off += SZ_WT;
  unsigned short* wkt  = (unsigned short*)(w + off); off += SZ_WT;
  unsigned short* wvtn = (unsigned short*)(w + off); off += SZ_WT;
  unsigned short* wpb  = (unsigned short*)(w + off); off += SZ_WPB;
  float* lrlog = (float*)(w + off); off += SZ_V16;
  float* wdlog = (float*)(w + off); off += SZ_V16;
  float* lr    = (float*)(w + off); off += SZ_V16;
  float* c     = (float*)(w + off); off += SZ_V16;
  float* s     = (float*)(w + off); off += SZ_V16;
  float* ecl   = (float*)(w + off); off += 256;
  float* bias2 = (float*)(w + off); off += (size_t)BB * DD * 4;

  // w2t (16.8 MB) + wkr (2 MB) alias the pb region: dead before k3_gemm_p writes pb.
  unsigned short* w2t = pb;
  unsigned short* wkr = pb + (size_t)BB * DD * DD;

  // q2 scratch lives in d_out's W_next region; overwritten by k3_gemm_wn afterwards.
  unsigned short* q2b = (unsigned short*)(out + (size_t)BL * DD);
  float* out2 = out + (size_t)BL * DD;

  k_prep_x<<<dim3(BL / 4), 256, 0, stream>>>(x, wlr, wwd, xb, lrlog, wdlog);
  k_prep_w<<<dim3(4096, 1, 4), 256, 0, stream>>>(wq, wk, wv, wqt, wkt, wvtn, wkr);
  k_prep_h<<<dim3((unsigned)((size_t)BB * DD * HH / 1024)), 256, 0, stream>>>(hid, wpb);
  k_scan<<<dim3(BB), 256, 0, stream>>>(lrlog, wdlog, lbl, blr, lbw, bwd, lr, c, s, ecl);
  k_bias2<<<dim3(BB * DD / 4), 256, 0, stream>>>(wpb, bk, bv, bias2);

  k3_gemm_m2<<<dim3(8, 32), 512, 0, stream>>>(wpb, wkr, wvtn, w2t);
  k3_gemm_q<<<dim3(8, 32), 512, 0, stream>>>(xb, wqt, bq, c, qb, q2b);
  k3_gemm_k<<<dim3(8, 32), 512, 0, stream>>>(xb, wkt, bk, s, kb, k2t);
  k3_gemm_u<<<dim3(8, 32), 512, 0, stream>>>(xb, w2t, bias2, ut);
  k3_gemm_p<<<dim3(8, 72), 512, 0, stream>>>(qb, kb, lr, c, pb);
  k3_gemm_y<<<dim3(8, 64), 512, 0, stream>>>(pb, ut, q2b, wpb, out);
  k3_gemm_wn<<<dim3(8, 32), 512, 0, stream>>>(ut, k2t, hid, ecl, out2);
}